// Round 1
// baseline (7659.576 us; speedup 1.0000x reference)
//
#include <hip/hip_runtime.h>
#include <math.h>

// Problem dims
#define NB   16
#define NC   1024
#define ND   256
#define NT_  9
#define TDIM 32

// SGEMM tile config
#define BM 128
#define BN 64
#define BK 16
#define NTHR 256

// ---------------------------------------------------------------------------
// copy h0 -> traj[:,0]
__global__ __launch_bounds__(256) void k_copy_h0(const float* __restrict__ h0,
                                                 float* __restrict__ out) {
  size_t idx = (size_t)blockIdx.x * blockDim.x + threadIdx.x; // float4 index
  size_t total = (size_t)NB * NC * ND / 4;
  if (idx >= total) return;
  size_t fe = idx * 4;
  size_t b = fe / ((size_t)NC * ND);
  size_t rem = fe % ((size_t)NC * ND);
  float4 v = *(const float4*)(h0 + fe);
  *(float4*)(out + (b * NT_) * (size_t)NC * ND + rem) = v;
}

// ---------------------------------------------------------------------------
// invdeg[b*NC+i] = 1 / max(sum_j adj[b,i,j], 1)
__global__ __launch_bounds__(256) void k_deg(const float* __restrict__ adj,
                                             float* __restrict__ invdeg) {
  int wave = threadIdx.x >> 6;
  int lane = threadIdx.x & 63;
  int row = blockIdx.x * 4 + wave; // 0 .. 16383
  const float* p = adj + (size_t)row * NC;
  float s = 0.f;
#pragma unroll
  for (int q = 0; q < 4; ++q) {
    float4 v = *(const float4*)(p + q * 256 + lane * 4);
    s += v.x + v.y + v.z + v.w;
  }
#pragma unroll
  for (int off = 32; off; off >>= 1) s += __shfl_down(s, off);
  if (lane == 0) invdeg[row] = 1.f / fmaxf(s, 1.f);
}

// ---------------------------------------------------------------------------
// b1eff[n] = b1[n] + sum_q te[q] * W1[(512+q)*ND + n]
// te = [sin(t*f_q) q<16, cos(t*f_q) q<16], f_q = exp(-ln(1e4)*q/16)
__global__ __launch_bounds__(256) void k_b1eff(const float* __restrict__ tg, int step,
                                               int stage, const float* __restrict__ W1,
                                               const float* __restrict__ b1,
                                               float* __restrict__ b1eff) {
  __shared__ float te[TDIM];
  int tid = threadIdx.x;
  float t0 = tg[step], t1 = tg[step + 1];
  float dt = t1 - t0;
  float frac = (stage == 0) ? 0.f : ((stage == 3) ? 1.f : 0.5f);
  float t = t0 + frac * dt;
  if (tid < 16) {
    float f = expf(-logf(10000.f) * (float)tid / 16.f);
    te[tid] = sinf(t * f);
    te[tid + 16] = cosf(t * f);
  }
  __syncthreads();
  float s = b1[tid];
#pragma unroll
  for (int q = 0; q < TDIM; ++q) s = fmaf(te[q], W1[(size_t)(512 + q) * ND + tid], s);
  b1eff[tid] = s;
}

// ---------------------------------------------------------------------------
// GEMM1: agg[b] = diag(invdeg[b]) * (adj[b] @ hin[b])   [1024x1024 @ 1024x256]
__global__ __launch_bounds__(NTHR) void k_agg(const float* __restrict__ adj,
                                              const float* __restrict__ hin, long hin_bs,
                                              const float* __restrict__ invdeg,
                                              float* __restrict__ agg) {
  const int b = blockIdx.z;
  const int m0 = blockIdx.x * BM;
  const int n0 = blockIdx.y * BN;
  const float* A = adj + (size_t)b * NC * NC;
  const float* Bp = hin + (size_t)b * hin_bs;
  __shared__ float As[BK][BM + 4];
  __shared__ float Bs[BK][BN + 4];
  const int tid = threadIdx.x;
  const int tx = tid & 15, ty = tid >> 4;
  float acc[8][4] = {};
  for (int k0 = 0; k0 < NC; k0 += BK) {
#pragma unroll
    for (int l = 0; l < 2; ++l) {
      int e = tid + l * NTHR;
      int row = e >> 2, c4 = (e & 3) << 2;
      float4 v = *(const float4*)(A + (size_t)(m0 + row) * NC + k0 + c4);
      As[c4 + 0][row] = v.x; As[c4 + 1][row] = v.y;
      As[c4 + 2][row] = v.z; As[c4 + 3][row] = v.w;
    }
    {
      int k = tid >> 4, c4 = (tid & 15) << 2;
      float4 v = *(const float4*)(Bp + (size_t)(k0 + k) * ND + n0 + c4);
      *(float4*)&Bs[k][c4] = v;
    }
    __syncthreads();
#pragma unroll
    for (int k = 0; k < BK; ++k) {
      float4 a0 = *(const float4*)&As[k][ty * 8];
      float4 a1 = *(const float4*)&As[k][ty * 8 + 4];
      float4 bv = *(const float4*)&Bs[k][tx * 4];
      float av[8] = {a0.x, a0.y, a0.z, a0.w, a1.x, a1.y, a1.z, a1.w};
      float bb[4] = {bv.x, bv.y, bv.z, bv.w};
#pragma unroll
      for (int i = 0; i < 8; ++i)
#pragma unroll
        for (int j = 0; j < 4; ++j) acc[i][j] = fmaf(av[i], bb[j], acc[i][j]);
    }
    __syncthreads();
  }
  float* Cp = agg + (size_t)b * NC * ND;
#pragma unroll
  for (int i = 0; i < 8; ++i) {
    int row = m0 + ty * 8 + i;
    float s = invdeg[b * NC + row];
    float4 v = make_float4(acc[i][0] * s, acc[i][1] * s, acc[i][2] * s, acc[i][3] * s);
    *(float4*)(Cp + (size_t)row * ND + n0 + tx * 4) = v;
  }
}

// ---------------------------------------------------------------------------
// GEMM2: u = tanh([hin | agg] @ W1[0:512] + b1eff)   M=16384, N=256, K=512
__global__ __launch_bounds__(NTHR) void k_mlp1(const float* __restrict__ hin, long hin_bs,
                                               const float* __restrict__ agg,
                                               const float* __restrict__ W1,
                                               const float* __restrict__ b1eff,
                                               float* __restrict__ u) {
  const int m0 = blockIdx.x * BM;
  const int n0 = blockIdx.y * BN;
  const int b = m0 >> 10;
  const int i0 = m0 & 1023;
  __shared__ float As[BK][BM + 4];
  __shared__ float Bs[BK][BN + 4];
  const int tid = threadIdx.x;
  const int tx = tid & 15, ty = tid >> 4;
  float acc[8][4] = {};
  for (int k0 = 0; k0 < 512; k0 += BK) {
    const float* Asrc;
    if (k0 < 256)
      Asrc = hin + (size_t)b * hin_bs + (size_t)i0 * ND + k0;
    else
      Asrc = agg + ((size_t)b * NC + i0) * ND + (k0 - 256);
#pragma unroll
    for (int l = 0; l < 2; ++l) {
      int e = tid + l * NTHR;
      int row = e >> 2, c4 = (e & 3) << 2;
      float4 v = *(const float4*)(Asrc + (size_t)row * ND + c4);
      As[c4 + 0][row] = v.x; As[c4 + 1][row] = v.y;
      As[c4 + 2][row] = v.z; As[c4 + 3][row] = v.w;
    }
    {
      int k = tid >> 4, c4 = (tid & 15) << 2;
      float4 v = *(const float4*)(W1 + (size_t)(k0 + k) * ND + n0 + c4);
      *(float4*)&Bs[k][c4] = v;
    }
    __syncthreads();
#pragma unroll
    for (int k = 0; k < BK; ++k) {
      float4 a0 = *(const float4*)&As[k][ty * 8];
      float4 a1 = *(const float4*)&As[k][ty * 8 + 4];
      float4 bv = *(const float4*)&Bs[k][tx * 4];
      float av[8] = {a0.x, a0.y, a0.z, a0.w, a1.x, a1.y, a1.z, a1.w};
      float bb[4] = {bv.x, bv.y, bv.z, bv.w};
#pragma unroll
      for (int i = 0; i < 8; ++i)
#pragma unroll
        for (int j = 0; j < 4; ++j) acc[i][j] = fmaf(av[i], bb[j], acc[i][j]);
    }
    __syncthreads();
  }
#pragma unroll
  for (int i = 0; i < 8; ++i) {
    int m = m0 + ty * 8 + i;
    float4 v;
    v.x = tanhf(acc[i][0] + b1eff[n0 + tx * 4 + 0]);
    v.y = tanhf(acc[i][1] + b1eff[n0 + tx * 4 + 1]);
    v.z = tanhf(acc[i][2] + b1eff[n0 + tx * 4 + 2]);
    v.w = tanhf(acc[i][3] + b1eff[n0 + tx * 4 + 3]);
    *(float4*)(u + (size_t)m * ND + n0 + tx * 4) = v;
  }
}

// ---------------------------------------------------------------------------
// GEMM3 + RK4 stage epilogue: f = u @ W2 + b2
// stage 0: accws = f;        htmp = hb + 0.5*dt*f
// stage 1: accws += 2f;      htmp = hb + 0.5*dt*f
// stage 2: accws += 2f;      htmp = hb + dt*f
// stage 3: out[:,step+1] = hb + dt/6*(accws + f)
__global__ __launch_bounds__(NTHR) void k_mlp2(const float* __restrict__ u,
                                               const float* __restrict__ W2,
                                               const float* __restrict__ b2,
                                               const float* __restrict__ tg, int step,
                                               int stage, float* __restrict__ out,
                                               float* __restrict__ accws,
                                               float* __restrict__ htmp) {
  const int m0 = blockIdx.x * BM;
  const int n0 = blockIdx.y * BN;
  __shared__ float As[BK][BM + 4];
  __shared__ float Bs[BK][BN + 4];
  const int tid = threadIdx.x;
  const int tx = tid & 15, ty = tid >> 4;
  float acc[8][4] = {};
  for (int k0 = 0; k0 < ND; k0 += BK) {
#pragma unroll
    for (int l = 0; l < 2; ++l) {
      int e = tid + l * NTHR;
      int row = e >> 2, c4 = (e & 3) << 2;
      float4 v = *(const float4*)(u + (size_t)(m0 + row) * ND + k0 + c4);
      As[c4 + 0][row] = v.x; As[c4 + 1][row] = v.y;
      As[c4 + 2][row] = v.z; As[c4 + 3][row] = v.w;
    }
    {
      int k = tid >> 4, c4 = (tid & 15) << 2;
      float4 v = *(const float4*)(W2 + (size_t)(k0 + k) * ND + n0 + c4);
      *(float4*)&Bs[k][c4] = v;
    }
    __syncthreads();
#pragma unroll
    for (int k = 0; k < BK; ++k) {
      float4 a0 = *(const float4*)&As[k][ty * 8];
      float4 a1 = *(const float4*)&As[k][ty * 8 + 4];
      float4 bv = *(const float4*)&Bs[k][tx * 4];
      float av[8] = {a0.x, a0.y, a0.z, a0.w, a1.x, a1.y, a1.z, a1.w};
      float bb[4] = {bv.x, bv.y, bv.z, bv.w};
#pragma unroll
      for (int i = 0; i < 8; ++i)
#pragma unroll
        for (int j = 0; j < 4; ++j) acc[i][j] = fmaf(av[i], bb[j], acc[i][j]);
    }
    __syncthreads();
  }
  const float t0 = tg[step], t1 = tg[step + 1];
  const float dt = t1 - t0;
#pragma unroll
  for (int i = 0; i < 8; ++i) {
    int m = m0 + ty * 8 + i;
    int b = m >> 10;
    int ii = m & 1023;
    int col = n0 + tx * 4;
    size_t hidx = (((size_t)b * NT_ + step) * NC + ii) * (size_t)ND + col;
    size_t widx = ((size_t)b * NC + ii) * (size_t)ND + col;
    float4 hb = *(const float4*)(out + hidx);
    float f[4];
#pragma unroll
    for (int j = 0; j < 4; ++j) f[j] = acc[i][j] + b2[col + j];
    if (stage == 0) {
      *(float4*)(accws + widx) = make_float4(f[0], f[1], f[2], f[3]);
      float4 ht = make_float4(hb.x + 0.5f * dt * f[0], hb.y + 0.5f * dt * f[1],
                              hb.z + 0.5f * dt * f[2], hb.w + 0.5f * dt * f[3]);
      *(float4*)(htmp + widx) = ht;
    } else if (stage == 1) {
      float4 a = *(const float4*)(accws + widx);
      a.x += 2.f * f[0]; a.y += 2.f * f[1]; a.z += 2.f * f[2]; a.w += 2.f * f[3];
      *(float4*)(accws + widx) = a;
      float4 ht = make_float4(hb.x + 0.5f * dt * f[0], hb.y + 0.5f * dt * f[1],
                              hb.z + 0.5f * dt * f[2], hb.w + 0.5f * dt * f[3]);
      *(float4*)(htmp + widx) = ht;
    } else if (stage == 2) {
      float4 a = *(const float4*)(accws + widx);
      a.x += 2.f * f[0]; a.y += 2.f * f[1]; a.z += 2.f * f[2]; a.w += 2.f * f[3];
      *(float4*)(accws + widx) = a;
      float4 ht = make_float4(hb.x + dt * f[0], hb.y + dt * f[1],
                              hb.z + dt * f[2], hb.w + dt * f[3]);
      *(float4*)(htmp + widx) = ht;
    } else {
      float4 a = *(const float4*)(accws + widx);
      float c = dt / 6.f;
      size_t oidx = (((size_t)b * NT_ + step + 1) * NC + ii) * (size_t)ND + col;
      float4 hn = make_float4(hb.x + c * (a.x + f[0]), hb.y + c * (a.y + f[1]),
                              hb.z + c * (a.z + f[2]), hb.w + c * (a.w + f[3]));
      *(float4*)(out + oidx) = hn;
    }
  }
}

// ---------------------------------------------------------------------------
extern "C" void kernel_launch(void* const* d_in, const int* in_sizes, int n_in,
                              void* d_out, int out_size, void* d_ws, size_t ws_size,
                              hipStream_t stream) {
  const float* h0 = (const float*)d_in[0];
  const float* tg = (const float*)d_in[1];
  const float* adj = (const float*)d_in[2];
  const float* W1 = (const float*)d_in[3];
  const float* b1 = (const float*)d_in[4];
  const float* W2 = (const float*)d_in[5];
  const float* b2 = (const float*)d_in[6];
  float* out = (float*)d_out;

  float* ws = (float*)d_ws;
  const size_t CD = (size_t)NC * ND;       // 262144
  float* invdeg = ws;                      // 16384
  float* agg = invdeg + 16384;             // 4194304
  float* u = agg + NB * CD;                // 4194304
  float* accws = u + NB * CD;              // 4194304
  float* htmp = accws + NB * CD;           // 4194304
  float* b1eff = htmp + NB * CD;           // 256

  k_copy_h0<<<dim3(4096), dim3(256), 0, stream>>>(h0, out);
  k_deg<<<dim3(4096), dim3(256), 0, stream>>>(adj, invdeg);

  for (int s = 0; s < NT_ - 1; ++s) {
    for (int st = 0; st < 4; ++st) {
      const float* hin;
      long hbs;
      if (st == 0) {
        hin = out + (size_t)s * CD;  // traj[:,s] with batch stride T*C*D
        hbs = (long)NT_ * CD;
      } else {
        hin = htmp;
        hbs = (long)CD;
      }
      k_b1eff<<<dim3(1), dim3(256), 0, stream>>>(tg, s, st, W1, b1, b1eff);
      k_agg<<<dim3(8, 4, 16), dim3(NTHR), 0, stream>>>(adj, hin, hbs, invdeg, agg);
      k_mlp1<<<dim3(128, 4), dim3(NTHR), 0, stream>>>(hin, hbs, agg, W1, b1eff, u);
      k_mlp2<<<dim3(128, 4), dim3(NTHR), 0, stream>>>(u, W2, b2, tg, s, st, out, accws,
                                                      htmp);
    }
  }
}

// Round 2
// 4271.103 us; speedup vs baseline: 1.7933x; 1.7933x over previous
//
#include <hip/hip_runtime.h>
#include <math.h>

// Problem dims
#define NB   16
#define NC   1024
#define ND   256
#define NT_  9
#define TDIM 32

// MFMA GEMM tile config: 128x64 tile, BK=32, 256 threads (4 waves, 2x2),
// wave tile 64x32 = 4x2 fragments of 16x16.
#define BM 128
#define BN 64
#define BK 32
#define NTHR 256

typedef _Float16 half8 __attribute__((ext_vector_type(8)));
typedef _Float16 half4v __attribute__((ext_vector_type(4)));
typedef float f32x4 __attribute__((ext_vector_type(4)));

#define GLL(gp, lp)                                                            \
  __builtin_amdgcn_global_load_lds(                                            \
      (const __attribute__((address_space(1))) void*)(gp),                     \
      (__attribute__((address_space(3))) void*)(lp), 16, 0, 0)

// ---------------------------------------------------------------------------
// copy h0 -> traj[:,0]
__global__ __launch_bounds__(256) void k_copy_h0(const float* __restrict__ h0,
                                                 float* __restrict__ out) {
  size_t idx = (size_t)blockIdx.x * blockDim.x + threadIdx.x; // float4 index
  size_t fe = idx * 4;
  size_t b = fe / ((size_t)NC * ND);
  size_t rem = fe % ((size_t)NC * ND);
  float4 v = *(const float4*)(h0 + fe);
  *(float4*)(out + (b * NT_) * (size_t)NC * ND + rem) = v;
}

// ---------------------------------------------------------------------------
// invdeg[b*NC+i] = 1 / max(sum_j adj[b,i,j], 1)
__global__ __launch_bounds__(256) void k_deg(const float* __restrict__ adj,
                                             float* __restrict__ invdeg) {
  int wave = threadIdx.x >> 6;
  int lane = threadIdx.x & 63;
  int row = blockIdx.x * 4 + wave; // 0 .. 16383
  const float* p = adj + (size_t)row * NC;
  float s = 0.f;
#pragma unroll
  for (int q = 0; q < 4; ++q) {
    float4 v = *(const float4*)(p + q * 256 + lane * 4);
    s += v.x + v.y + v.z + v.w;
  }
#pragma unroll
  for (int off = 32; off; off >>= 1) s += __shfl_down(s, off);
  if (lane == 0) invdeg[row] = 1.f / fmaxf(s, 1.f);
}

// ---------------------------------------------------------------------------
// b1eff[n] = b1[n] + sum_q te[q] * W1[(512+q)*ND + n]
__global__ __launch_bounds__(256) void k_b1eff(const float* __restrict__ tg, int step,
                                               int stage, const float* __restrict__ W1,
                                               const float* __restrict__ b1,
                                               float* __restrict__ b1eff) {
  __shared__ float te[TDIM];
  int tid = threadIdx.x;
  float t0 = tg[step], t1 = tg[step + 1];
  float dt = t1 - t0;
  float frac = (stage == 0) ? 0.f : ((stage == 3) ? 1.f : 0.5f);
  float t = t0 + frac * dt;
  if (tid < 16) {
    float f = expf(-logf(10000.f) * (float)tid / 16.f);
    te[tid] = sinf(t * f);
    te[tid + 16] = cosf(t * f);
  }
  __syncthreads();
  float s = b1[tid];
#pragma unroll
  for (int q = 0; q < TDIM; ++q) s = fmaf(te[q], W1[(size_t)(512 + q) * ND + tid], s);
  b1eff[tid] = s;
}

// ---------------------------------------------------------------------------
// adjacency f32 -> fp16 hi/lo split (same layout)
__global__ __launch_bounds__(256) void k_split_adj(const float* __restrict__ adj,
                                                   _Float16* __restrict__ aH,
                                                   _Float16* __restrict__ aL) {
  size_t i4 = (size_t)blockIdx.x * 256 + threadIdx.x; // float4 index
  float4 v = *(const float4*)(adj + i4 * 4);
  half4v h, l;
  float vv[4] = {v.x, v.y, v.z, v.w};
#pragma unroll
  for (int q = 0; q < 4; ++q) {
    _Float16 hh = (_Float16)vv[q];
    h[q] = hh;
    l[q] = (_Float16)(vv[q] - (float)hh);
  }
  *(half4v*)(aH + i4 * 4) = h;
  *(half4v*)(aL + i4 * 4) = l;
}

// ---------------------------------------------------------------------------
// W1[0:512]^T and W2^T -> fp16 hi/lo  (W1T [256][512], W2T [256][256])
__global__ __launch_bounds__(256) void k_split_w(const float* __restrict__ W1,
                                                 const float* __restrict__ W2,
                                                 _Float16* __restrict__ W1TH,
                                                 _Float16* __restrict__ W1TL,
                                                 _Float16* __restrict__ W2TH,
                                                 _Float16* __restrict__ W2TL) {
  int o = blockIdx.x * 256 + threadIdx.x;
  if (o < 256 * 512) {
    int n = o >> 9, k = o & 511;
    float v = W1[(size_t)k * ND + n];
    _Float16 h = (_Float16)v;
    W1TH[o] = h;
    W1TL[o] = (_Float16)(v - (float)h);
  } else {
    int o2 = o - 256 * 512;
    int n = o2 >> 8, k = o2 & 255;
    float v = W2[(size_t)k * ND + n];
    _Float16 h = (_Float16)v;
    W2TH[o2] = h;
    W2TL[o2] = (_Float16)(v - (float)h);
  }
}

// ---------------------------------------------------------------------------
// h (f32, [b][c][d] with batch stride bs) -> hH/hL normal [b][c][d]
//                                          + hTH/hTL transposed [b][d][c]
__global__ __launch_bounds__(256) void k_htsplit(const float* __restrict__ src, long bs,
                                                 _Float16* __restrict__ hH,
                                                 _Float16* __restrict__ hL,
                                                 _Float16* __restrict__ hTH,
                                                 _Float16* __restrict__ hTL) {
  __shared__ float tile[64][65];
  int b = blockIdx.z, c0 = blockIdx.x * 64, d0 = blockIdx.y * 64;
  int t = threadIdx.x;
#pragma unroll
  for (int it = 0; it < 16; ++it) {
    int e = it * 256 + t;
    int cl = e >> 6, dl = e & 63;
    float v = src[(size_t)b * bs + (size_t)(c0 + cl) * ND + d0 + dl];
    _Float16 h = (_Float16)v;
    _Float16 lo = (_Float16)(v - (float)h);
    size_t ni = ((size_t)b * NC + c0 + cl) * ND + d0 + dl;
    hH[ni] = h;
    hL[ni] = lo;
    tile[dl][cl] = v;
  }
  __syncthreads();
#pragma unroll
  for (int it = 0; it < 16; ++it) {
    int e = it * 256 + t;
    int dl = e >> 6, cl = e & 63;
    float v = tile[dl][cl];
    _Float16 h = (_Float16)v;
    _Float16 lo = (_Float16)(v - (float)h);
    size_t ti = ((size_t)b * ND + d0 + dl) * NC + c0 + cl;
    hTH[ti] = h;
    hTL[ti] = lo;
  }
}

// ---------------------------------------------------------------------------
// shared GEMM machinery: A [BM rows][K], B^T [BN rows][K], both fp16 hi/lo,
// K-major, staged to LDS planes [k/8][row][8] via global_load_lds(16B).
__device__ __forceinline__ void stage_A(const _Float16* sH, const _Float16* sL,
                                        size_t sA, _Float16* AsH, _Float16* AsL,
                                        int wid, int lane) {
#pragma unroll
  for (int c = 0; c < 2; ++c) {
    int nb = c * 256 + wid * 64; // uniform chunk base
    int n = nb + lane;
    int g = n >> 7, r = n & 127;
    GLL(sH + (size_t)r * sA + 8 * g, AsH + (size_t)nb * 8);
    GLL(sL + (size_t)r * sA + 8 * g, AsL + (size_t)nb * 8);
  }
}

__device__ __forceinline__ void stage_B(const _Float16* sH, const _Float16* sL,
                                        size_t sB, _Float16* BsH, _Float16* BsL,
                                        int wid, int lane) {
  int nb = wid * 64;
  int n = nb + lane;
  int g = n >> 6, r = n & 63;
  GLL(sH + (size_t)r * sB + 8 * g, BsH + (size_t)nb * 8);
  GLL(sL + (size_t)r * sB + 8 * g, BsL + (size_t)nb * 8);
}

__device__ __forceinline__ void mfma_step(const _Float16* AsH, const _Float16* AsL,
                                          const _Float16* BsH, const _Float16* BsL,
                                          int wm, int wn, int lane,
                                          f32x4 acc[4][2]) {
  int g = lane >> 4, r = lane & 15;
  half8 AHf[4], ALf[4], BHf[2], BLf[2];
#pragma unroll
  for (int i = 0; i < 4; ++i) {
    int ch = g * 128 + wm * 64 + i * 16 + r;
    AHf[i] = ((const half8*)AsH)[ch];
    ALf[i] = ((const half8*)AsL)[ch];
  }
#pragma unroll
  for (int j = 0; j < 2; ++j) {
    int ch = g * 64 + wn * 32 + j * 16 + r;
    BHf[j] = ((const half8*)BsH)[ch];
    BLf[j] = ((const half8*)BsL)[ch];
  }
#pragma unroll
  for (int i = 0; i < 4; ++i)
#pragma unroll
    for (int j = 0; j < 2; ++j) {
      acc[i][j] = __builtin_amdgcn_mfma_f32_16x16x32_f16(AHf[i], BHf[j], acc[i][j], 0, 0, 0);
      acc[i][j] = __builtin_amdgcn_mfma_f32_16x16x32_f16(AHf[i], BLf[j], acc[i][j], 0, 0, 0);
      acc[i][j] = __builtin_amdgcn_mfma_f32_16x16x32_f16(ALf[i], BHf[j], acc[i][j], 0, 0, 0);
    }
}

#define GEMM_PRE()                                                             \
  __shared__ __align__(16) _Float16 AsH[4 * 128 * 8];                          \
  __shared__ __align__(16) _Float16 AsL[4 * 128 * 8];                          \
  __shared__ __align__(16) _Float16 BsH[4 * 64 * 8];                           \
  __shared__ __align__(16) _Float16 BsL[4 * 64 * 8];                           \
  const int tid = threadIdx.x;                                                 \
  const int lane = tid & 63, wid = tid >> 6;                                   \
  const int wm = wid >> 1, wn = wid & 1;                                       \
  f32x4 acc[4][2] = {};

// ---------------------------------------------------------------------------
// GEMM1: agg[b] = diag(invdeg[b]) * (adj[b] @ h[b]); epilogue splits to fp16.
__global__ __launch_bounds__(NTHR) void k_agg(const _Float16* __restrict__ adjH,
                                              const _Float16* __restrict__ adjL,
                                              const _Float16* __restrict__ hTH,
                                              const _Float16* __restrict__ hTL,
                                              const float* __restrict__ invdeg,
                                              _Float16* __restrict__ aggH,
                                              _Float16* __restrict__ aggL) {
  const int b = blockIdx.z;
  const int m0 = blockIdx.x * BM;
  const int n0 = blockIdx.y * BN;
  GEMM_PRE();
  const _Float16* A_H = adjH + (size_t)b * NC * NC + (size_t)m0 * NC;
  const _Float16* A_L = adjL + (size_t)b * NC * NC + (size_t)m0 * NC;
  const _Float16* B_H = hTH + (size_t)b * ND * NC + (size_t)n0 * NC;
  const _Float16* B_L = hTL + (size_t)b * ND * NC + (size_t)n0 * NC;
  for (int k0 = 0; k0 < NC; k0 += BK) {
    stage_A(A_H + k0, A_L + k0, NC, AsH, AsL, wid, lane);
    stage_B(B_H + k0, B_L + k0, NC, BsH, BsL, wid, lane);
    asm volatile("s_waitcnt vmcnt(0)" ::: "memory");
    __syncthreads();
    mfma_step(AsH, AsL, BsH, BsL, wm, wn, lane, acc);
    __syncthreads();
  }
  int r15 = lane & 15, rg = (lane >> 4) * 4;
#pragma unroll
  for (int i = 0; i < 4; ++i) {
#pragma unroll
    for (int j = 0; j < 2; ++j) {
      int col = n0 + wn * 32 + j * 16 + r15;
#pragma unroll
      for (int q = 0; q < 4; ++q) {
        int m = m0 + wm * 64 + i * 16 + rg + q;
        float v = acc[i][j][q] * invdeg[b * NC + m];
        _Float16 h = (_Float16)v;
        size_t idx = ((size_t)b * NC + m) * ND + col;
        aggH[idx] = h;
        aggL[idx] = (_Float16)(v - (float)h);
      }
    }
  }
}

// ---------------------------------------------------------------------------
// GEMM2: u = tanh([h | agg] @ W1[0:512] + b1eff); epilogue splits u to fp16.
__global__ __launch_bounds__(NTHR) void k_mlp1(const _Float16* __restrict__ hH,
                                               const _Float16* __restrict__ hL,
                                               const _Float16* __restrict__ aggH,
                                               const _Float16* __restrict__ aggL,
                                               const _Float16* __restrict__ W1TH,
                                               const _Float16* __restrict__ W1TL,
                                               const float* __restrict__ b1eff,
                                               _Float16* __restrict__ uH,
                                               _Float16* __restrict__ uL) {
  const int m0 = blockIdx.x * BM;
  const int n0 = blockIdx.y * BN;
  const int b = m0 >> 10, c0 = m0 & 1023;
  GEMM_PRE();
  const size_t abase = ((size_t)b * NC + c0) * ND;
  for (int k0 = 0; k0 < 512; k0 += BK) {
    const _Float16 *sH, *sL;
    if (k0 < 256) {
      sH = hH + abase + k0;
      sL = hL + abase + k0;
    } else {
      sH = aggH + abase + (k0 - 256);
      sL = aggL + abase + (k0 - 256);
    }
    stage_A(sH, sL, ND, AsH, AsL, wid, lane);
    stage_B(W1TH + (size_t)n0 * 512 + k0, W1TL + (size_t)n0 * 512 + k0, 512, BsH, BsL,
            wid, lane);
    asm volatile("s_waitcnt vmcnt(0)" ::: "memory");
    __syncthreads();
    mfma_step(AsH, AsL, BsH, BsL, wm, wn, lane, acc);
    __syncthreads();
  }
  int r15 = lane & 15, rg = (lane >> 4) * 4;
#pragma unroll
  for (int i = 0; i < 4; ++i) {
#pragma unroll
    for (int j = 0; j < 2; ++j) {
      int col = n0 + wn * 32 + j * 16 + r15;
#pragma unroll
      for (int q = 0; q < 4; ++q) {
        int m = m0 + wm * 64 + i * 16 + rg + q;
        float v = tanhf(acc[i][j][q] + b1eff[col]);
        _Float16 h = (_Float16)v;
        size_t idx = (size_t)m * ND + col;
        uH[idx] = h;
        uL[idx] = (_Float16)(v - (float)h);
      }
    }
  }
}

// ---------------------------------------------------------------------------
// GEMM3 + RK4 stage epilogue (f32): f = u @ W2 + b2
__global__ __launch_bounds__(NTHR) void k_mlp2(const _Float16* __restrict__ uH,
                                               const _Float16* __restrict__ uL,
                                               const _Float16* __restrict__ W2TH,
                                               const _Float16* __restrict__ W2TL,
                                               const float* __restrict__ b2,
                                               const float* __restrict__ tg, int step,
                                               int stage, float* __restrict__ out,
                                               float* __restrict__ accws,
                                               float* __restrict__ htmp) {
  const int m0 = blockIdx.x * BM;
  const int n0 = blockIdx.y * BN;
  GEMM_PRE();
  for (int k0 = 0; k0 < ND; k0 += BK) {
    stage_A(uH + (size_t)m0 * ND + k0, uL + (size_t)m0 * ND + k0, ND, AsH, AsL, wid,
            lane);
    stage_B(W2TH + (size_t)n0 * ND + k0, W2TL + (size_t)n0 * ND + k0, ND, BsH, BsL, wid,
            lane);
    asm volatile("s_waitcnt vmcnt(0)" ::: "memory");
    __syncthreads();
    mfma_step(AsH, AsL, BsH, BsL, wm, wn, lane, acc);
    __syncthreads();
  }
  const float t0 = tg[step], t1 = tg[step + 1];
  const float dt = t1 - t0;
  int r15 = lane & 15, rg = (lane >> 4) * 4;
#pragma unroll
  for (int i = 0; i < 4; ++i) {
#pragma unroll
    for (int j = 0; j < 2; ++j) {
      int col = n0 + wn * 32 + j * 16 + r15;
#pragma unroll
      for (int q = 0; q < 4; ++q) {
        int m = m0 + wm * 64 + i * 16 + rg + q;
        int b = m >> 10, ii = m & 1023;
        float f = acc[i][j][q] + b2[col];
        size_t hidx = (((size_t)b * NT_ + step) * NC + ii) * (size_t)ND + col;
        size_t widx = (size_t)m * ND + col;
        float hb = out[hidx];
        if (stage == 0) {
          accws[widx] = f;
          htmp[widx] = hb + 0.5f * dt * f;
        } else if (stage == 1) {
          accws[widx] += 2.f * f;
          htmp[widx] = hb + 0.5f * dt * f;
        } else if (stage == 2) {
          accws[widx] += 2.f * f;
          htmp[widx] = hb + dt * f;
        } else {
          size_t oidx = (((size_t)b * NT_ + step + 1) * NC + ii) * (size_t)ND + col;
          out[oidx] = hb + (dt / 6.f) * (accws[widx] + f);
        }
      }
    }
  }
}

// ---------------------------------------------------------------------------
extern "C" void kernel_launch(void* const* d_in, const int* in_sizes, int n_in,
                              void* d_out, int out_size, void* d_ws, size_t ws_size,
                              hipStream_t stream) {
  const float* h0 = (const float*)d_in[0];
  const float* tg = (const float*)d_in[1];
  const float* adj = (const float*)d_in[2];
  const float* W1 = (const float*)d_in[3];
  const float* b1 = (const float*)d_in[4];
  const float* W2 = (const float*)d_in[5];
  const float* b2 = (const float*)d_in[6];
  float* out = (float*)d_out;

  const size_t CD = (size_t)NC * ND; // 262144
  char* w = (char*)d_ws;
  float* invdeg = (float*)w;    w += (size_t)16384 * 4;
  float* b1eff = (float*)w;     w += 1024;
  float* accws = (float*)w;     w += (size_t)NB * CD * 4;
  float* htmp = (float*)w;      w += (size_t)NB * CD * 4;
  _Float16* adjH = (_Float16*)w; w += (size_t)NB * NC * NC * 2;
  _Float16* adjL = (_Float16*)w; w += (size_t)NB * NC * NC * 2;
  _Float16* hH = (_Float16*)w;   w += (size_t)NB * CD * 2;
  _Float16* hL = (_Float16*)w;   w += (size_t)NB * CD * 2;
  _Float16* hTH = (_Float16*)w;  w += (size_t)NB * CD * 2;
  _Float16* hTL = (_Float16*)w;  w += (size_t)NB * CD * 2;
  _Float16* aggH = (_Float16*)w; w += (size_t)NB * CD * 2;
  _Float16* aggL = (_Float16*)w; w += (size_t)NB * CD * 2;
  _Float16* W1TH = (_Float16*)w; w += (size_t)256 * 512 * 2;
  _Float16* W1TL = (_Float16*)w; w += (size_t)256 * 512 * 2;
  _Float16* W2TH = (_Float16*)w; w += (size_t)256 * 256 * 2;
  _Float16* W2TL = (_Float16*)w; w += (size_t)256 * 256 * 2;
  // u aliases hT (hT is dead after k_agg; u is written by k_mlp1 afterwards)
  _Float16* uH = hTH;
  _Float16* uL = hTL;

  k_copy_h0<<<dim3(4096), dim3(256), 0, stream>>>(h0, out);
  k_deg<<<dim3(4096), dim3(256), 0, stream>>>(adj, invdeg);
  k_split_adj<<<dim3(16384), dim3(256), 0, stream>>>(adj, adjH, adjL);
  k_split_w<<<dim3(768), dim3(256), 0, stream>>>(W1, W2, W1TH, W1TL, W2TH, W2TL);

  for (int s = 0; s < NT_ - 1; ++s) {
    for (int st = 0; st < 4; ++st) {
      const float* hsrc;
      long hbs;
      if (st == 0) {
        hsrc = out + (size_t)s * CD; // traj[:,s], batch stride T*C*D
        hbs = (long)NT_ * CD;
      } else {
        hsrc = htmp;
        hbs = (long)CD;
      }
      k_b1eff<<<dim3(1), dim3(256), 0, stream>>>(tg, s, st, W1, b1, b1eff);
      k_htsplit<<<dim3(16, 4, 16), dim3(256), 0, stream>>>(hsrc, hbs, hH, hL, hTH, hTL);
      k_agg<<<dim3(8, 4, 16), dim3(NTHR), 0, stream>>>(adjH, adjL, hTH, hTL, invdeg,
                                                       aggH, aggL);
      k_mlp1<<<dim3(128, 4), dim3(NTHR), 0, stream>>>(hH, hL, aggH, aggL, W1TH, W1TL,
                                                      b1eff, uH, uL);
      k_mlp2<<<dim3(128, 4), dim3(NTHR), 0, stream>>>(uH, uL, W2TH, W2TL, b2, tg, s, st,
                                                      out, accws, htmp);
    }
  }
}